// Round 13
// baseline (84.871 us; speedup 1.0000x reference)
//
#include <hip/hip_runtime.h>
#include <stdint.h>

#define BB 64
#define CC 3
#define HH 512
#define WW 512
#define TILE 32
#define MAXBH 48
#define MAXBW 52
#define PLST 52  // plane row stride (dwords) — R9 layout (best measured)
#define NT 4     // tiles per block (pipelined)

typedef float f32x2 __attribute__((ext_vector_type(2)));
typedef float f32x4 __attribute__((ext_vector_type(4)));

__device__ __forceinline__ void pix2in(float x, float y,
                                       float cs, float sn, float tx, float ty,
                                       float& ix, float& iy)
{
    float gx = (2.0f * x + 1.0f) * (1.0f / (float)WW) - 1.0f;
    float gy = (2.0f * y + 1.0f) * (1.0f / (float)HH) - 1.0f;
    float gxt = cs * gx - sn * gy + tx;
    float gyt = sn * gx + cs * gy + ty;
    ix = ((gxt + 1.0f) * (float)WW - 1.0f) * 0.5f;
    iy = ((gyt + 1.0f) * (float)HH - 1.0f) * 0.5f;
}

// ws layout: float prm[64*4] (cs,sn,tx,ty per batch), then uint32 desc[16384]
__global__ __launch_bounds__(256) void warp_setup(
    const float* __restrict__ rot, const float* __restrict__ trans,
    const float* __restrict__ scale, float* __restrict__ ws)
{
    const int i = blockIdx.x * 256 + threadIdx.x;   // 0..16383 = b*256+t
    const int b = i >> 8, t = i & 255;
    const float r = rot[b];
    const float inv_s = 1.0f / scale[b];
    const float cs = cosf(r) * inv_s;
    const float sn = sinf(r) * inv_s;
    const float tx = trans[2 * b], ty = trans[2 * b + 1];
    if (t == 0)
        reinterpret_cast<float4*>(ws)[b] = make_float4(cs, sn, tx, ty);

    const int oy0 = (t >> 4) * TILE;
    const int ox0 = (t & 15) * TILE;
    float ixa, iya, ixb, iyb, ixc, iyc, ixd, iyd;
    pix2in((float)ox0,              (float)oy0,              cs, sn, tx, ty, ixa, iya);
    pix2in((float)(ox0 + TILE - 1), (float)oy0,              cs, sn, tx, ty, ixb, iyb);
    pix2in((float)ox0,              (float)(oy0 + TILE - 1), cs, sn, tx, ty, ixc, iyc);
    pix2in((float)(ox0 + TILE - 1), (float)(oy0 + TILE - 1), cs, sn, tx, ty, ixd, iyd);
    const float minix = fminf(fminf(ixa, ixb), fminf(ixc, ixd));
    const float maxix = fmaxf(fmaxf(ixa, ixb), fmaxf(ixc, ixd));
    const float miniy = fminf(fminf(iya, iyb), fminf(iyc, iyd));
    const float maxiy = fmaxf(fmaxf(iya, iyb), fmaxf(iyc, iyd));
    const int bx0 = (int)floorf(minix) - 1;
    const int bx1 = (int)floorf(maxix) + 2;
    const int by0 = (int)floorf(miniy) - 1;
    const int by1 = (int)floorf(maxiy) + 2;
    int bx0c = bx0 & ~3;
    const int bw = bx1 - bx0c + 1;
    const int bh = by1 - by0 + 1;

    const uint32_t fit      = (bw <= MAXBW && bh <= MAXBH) ? 1u : 0u;
    const uint32_t interior = (bx0c >= 0 && bx1 < WW && by0 >= 0 && by1 < HH) ? 1u : 0u;
    const int bx0s = min(max(bx0c, -2048), 2047);
    const int by0s = min(max(by0,  -2048), 2047);
    const int bhs  = min(bh, 63);
    const uint32_t desc = ((uint32_t)bx0s & 0xFFFu)
                        | (((uint32_t)by0s & 0xFFFu) << 12)
                        | ((uint32_t)bhs << 24)
                        | (fit << 30) | (interior << 31);
    reinterpret_cast<uint32_t*>(ws)[256 + i] = desc;
}

struct Stage { f32x4 a0, b0, c0, a1, b1, c1; };

__device__ __forceinline__ Stage stage_load(uint32_t desc, const float* __restrict__ imb,
                                            long plane, int q, int ql)
{
    Stage s = {};
    const bool fit = (desc >> 30) & 1;
    if (!fit || ql >= 13) return s;
    const int  bx0c     = ((int)(desc << 20)) >> 20;
    const int  by0      = ((int)(desc << 8))  >> 20;
    const int  bh       = (desc >> 24) & 63;
    const bool interior = (desc >> 31) & 1;
    const int  xb       = ql * 4;

    if (interior && (bx0c + 51 < WW)) {
        const float* pr = imb + (long)(by0 + q) * WW + (bx0c + xb);
        if (q < bh) {
            s.a0 = *reinterpret_cast<const f32x4*>(pr);
            s.b0 = *reinterpret_cast<const f32x4*>(pr + plane);
            s.c0 = *reinterpret_cast<const f32x4*>(pr + 2 * plane);
        }
        if (q + 32 < bh) {
            const float* p2 = pr + 32 * WW;
            s.a1 = *reinterpret_cast<const f32x4*>(p2);
            s.b1 = *reinterpret_cast<const f32x4*>(p2 + plane);
            s.c1 = *reinterpret_cast<const f32x4*>(p2 + 2 * plane);
        }
    } else {
        #pragma unroll
        for (int h = 0; h < 2; ++h) {
            const int r = q + h * 32;
            if (r >= bh) continue;
            const int grow = by0 + r;
            const bool rowok = (grow >= 0) && (grow < HH);
            const float* pr = imb + (long)grow * WW;
            f32x4 a = {0.f,0.f,0.f,0.f}, bv = a, cv = a;
            #pragma unroll
            for (int k = 0; k < 4; ++k) {
                const int gcol = bx0c + xb + k;
                if (rowok && gcol >= 0 && gcol < WW) {
                    a[k]  = pr[gcol];
                    bv[k] = pr[(long)gcol + plane];
                    cv[k] = pr[(long)gcol + 2 * plane];
                }
            }
            if (h == 0) { s.a0 = a; s.b0 = bv; s.c0 = cv; }
            else        { s.a1 = a; s.b1 = bv; s.c1 = cv; }
        }
    }
    return s;
}

__device__ __forceinline__ void lds_write(const Stage& s, uint32_t desc,
                                          float* __restrict__ pl, int q, int ql)
{
    const bool fit = (desc >> 30) & 1;
    if (!fit || ql >= 13) return;
    const int bh = (desc >> 24) & 63;
    const int xb = ql * 4;
    if (q < bh) {
        *reinterpret_cast<f32x4*>(pl + 0 * (MAXBH * PLST) + q * PLST + xb) = s.a0;
        *reinterpret_cast<f32x4*>(pl + 1 * (MAXBH * PLST) + q * PLST + xb) = s.b0;
        *reinterpret_cast<f32x4*>(pl + 2 * (MAXBH * PLST) + q * PLST + xb) = s.c0;
    }
    if (q + 32 < bh) {
        *reinterpret_cast<f32x4*>(pl + 0 * (MAXBH * PLST) + (q + 32) * PLST + xb) = s.a1;
        *reinterpret_cast<f32x4*>(pl + 1 * (MAXBH * PLST) + (q + 32) * PLST + xb) = s.b1;
        *reinterpret_cast<f32x4*>(pl + 2 * (MAXBH * PLST) + (q + 32) * PLST + xb) = s.c1;
    }
}

template <bool INTERIOR>
__device__ __forceinline__ void compute_store(
    const float* __restrict__ pl, float* __restrict__ outb,
    int tid, int ox0, int oy0, int bx0c, int by0,
    float cs, float sn, float tpx, float tpy, long plane)
{
    const int row = tid >> 4;            // 0..31
    const int xp  = (tid & 15) * 2;      // 0,2,...,30
    const int oy  = oy0 + row;
    const int oxb = ox0 + xp;

    float ix0, iy0;
    pix2in((float)oxb, (float)oy, cs, sn, tpx, tpy, ix0, iy0);

    float r0[2], r1[2], r2[2];
    #pragma unroll
    for (int e = 0; e < 2; ++e) {
        const float ix = fmaf((float)e, cs, ix0);   // affine: +cs per output x
        const float iy = fmaf((float)e, sn, iy0);
        const float x0f = floorf(ix), y0f = floorf(iy);
        const float wx1 = ix - x0f,  wy1 = iy - y0f;
        const float wx0 = 1.0f - wx1, wy0 = 1.0f - wy1;
        const int x0 = (int)x0f, y0 = (int)y0f;

        float w00 = wy0 * wx0, w01 = wy0 * wx1, w10 = wy1 * wx0, w11 = wy1 * wx1;
        if (!INTERIOR) {
            const int x1 = x0 + 1, y1 = y0 + 1;
            const float vx0 = (x0 >= 0 && x0 < WW) ? 1.0f : 0.0f;
            const float vx1 = (x1 >= 0 && x1 < WW) ? 1.0f : 0.0f;
            const float vy0 = (y0 >= 0 && y0 < HH) ? 1.0f : 0.0f;
            const float vy1 = (y1 >= 0 && y1 < HH) ? 1.0f : 0.0f;
            w00 *= vy0 * vx0; w01 *= vy0 * vx1; w10 *= vy1 * vx0; w11 *= vy1 * vx1;
        }

        const int idx = (y0 - by0) * PLST + (x0 - bx0c);
        const float* pb = pl + idx;
        #pragma unroll
        for (int c = 0; c < CC; ++c) {
            const float* pc = pb + c * (MAXBH * PLST);
            const float v = w00 * pc[0] + w01 * pc[1]
                          + w10 * pc[PLST] + w11 * pc[PLST + 1];
            if (c == 0) r0[e] = v; else if (c == 1) r1[e] = v; else r2[e] = v;
        }
    }
    const long ob = (long)oy * WW + oxb;
    const f32x2 o0 = {r0[0], r0[1]};
    const f32x2 o1 = {r1[0], r1[1]};
    const f32x2 o2 = {r2[0], r2[1]};
    __builtin_nontemporal_store(o0, reinterpret_cast<f32x2*>(outb + ob));
    __builtin_nontemporal_store(o1, reinterpret_cast<f32x2*>(outb + plane + ob));
    __builtin_nontemporal_store(o2, reinterpret_cast<f32x2*>(outb + 2 * plane + ob));
}

__device__ __forceinline__ void fallback_tile(
    const float* __restrict__ imb, float* __restrict__ outb,
    int tid, int ox0, int oy0,
    float cs, float sn, float tpx, float tpy, long plane)
{
    #pragma unroll
    for (int k = 0; k < 2; ++k) {
        const int pidx = tid + k * 512;
        const int py = pidx >> 5;
        const int px = pidx & 31;
        const int ox = ox0 + px, oy = oy0 + py;

        float ix, iy;
        pix2in((float)ox, (float)oy, cs, sn, tpx, tpy, ix, iy);
        const float x0f = floorf(ix), y0f = floorf(iy);
        const float wx1 = ix - x0f,  wy1 = iy - y0f;
        const int x0 = (int)x0f, y0 = (int)y0f;
        const int x1 = x0 + 1,  y1 = y0 + 1;

        const float vx0 = (x0 >= 0 && x0 < WW) ? 1.0f : 0.0f;
        const float vx1 = (x1 >= 0 && x1 < WW) ? 1.0f : 0.0f;
        const float vy0 = (y0 >= 0 && y0 < HH) ? 1.0f : 0.0f;
        const float vy1 = (y1 >= 0 && y1 < HH) ? 1.0f : 0.0f;

        const int x0c = min(max(x0, 0), WW - 1);
        const int x1c = min(max(x1, 0), WW - 1);
        const int y0c = min(max(y0, 0), HH - 1);
        const int y1c = min(max(y1, 0), HH - 1);

        const float w00 = (1.0f - wy1) * (1.0f - wx1) * vy0 * vx0;
        const float w01 = (1.0f - wy1) * wx1          * vy0 * vx1;
        const float w10 = wy1          * (1.0f - wx1) * vy1 * vx0;
        const float w11 = wy1          * wx1          * vy1 * vx1;

        const int o00 = y0c * WW + x0c, o01 = y0c * WW + x1c;
        const int o10 = y1c * WW + x0c, o11 = y1c * WW + x1c;
        const int ob = oy * WW + ox;
        #pragma unroll
        for (int c = 0; c < CC; ++c) {
            const float* pc = imb + (long)c * plane;
            const float v = w00 * pc[o00] + w01 * pc[o01]
                          + w10 * pc[o10] + w11 * pc[o11];
            __builtin_nontemporal_store(v, &outb[(long)c * plane + ob]);
        }
    }
}

__global__ __launch_bounds__(512) void warp_tiled(
    const float* __restrict__ img, const float* __restrict__ ws,
    float* __restrict__ out)
{
    __shared__ __align__(16) float pl[CC][MAXBH][PLST];   // 29.3 KB, R9 layout

    // 4096 blocks; XCD chunk swizzle: each XCD owns 512 consecutive = 8 whole batches
    const int g    = blockIdx.x;
    const int swzb = (g & 7) * ((BB * 64) / 8) + (g >> 3);
    const int b    = swzb >> 6;           // batch (64 blocks per batch)
    const int blk  = swzb & 63;
    const int ty   = blk >> 2;            // tile row 0..15
    const int qx   = (blk & 3) * NT;      // first tile-x of this block's quad
    const int oy0  = ty * TILE;

    const float4 p = reinterpret_cast<const float4*>(ws)[b];
    const float cs = p.x, sn = p.y, tpx = p.z, tpy = p.w;
    const uint32_t* dptr = reinterpret_cast<const uint32_t*>(ws) + 256 + b * 256 + ty * 16 + qx;

    const long plane = (long)HH * WW;
    const float* imb = img + (long)b * CC * plane;
    float* outb      = out + (long)b * CC * plane;
    const int tid = threadIdx.x;
    const int q  = tid >> 4;              // 0..31 staging row group
    const int ql = tid & 15;              // 13 active staging lanes

    // ---- prologue: stage tile 0 ----
    uint32_t dcur = dptr[0];
    {
        Stage s0 = stage_load(dcur, imb, plane, q, ql);
        lds_write(s0, dcur, &pl[0][0][0], q, ql);
    }
    __syncthreads();

    // ---- pipelined loop over NT tiles ----
    #pragma unroll
    for (int tt = 0; tt < NT; ++tt) {
        const int ox0 = (qx + tt) * TILE;

        uint32_t dnext = 0;
        Stage sn_;
        if (tt + 1 < NT) {
            dnext = dptr[tt + 1];
            sn_ = stage_load(dnext, imb, plane, q, ql);   // VMEM issued before compute
        }

        const int  bx0c     = ((int)(dcur << 20)) >> 20;
        const int  by0      = ((int)(dcur << 8))  >> 20;
        const bool fit      = (dcur >> 30) & 1;
        const bool interior = (dcur >> 31) & 1;

        if (fit) {
            if (interior)
                compute_store<true >(&pl[0][0][0], outb, tid, ox0, oy0, bx0c, by0, cs, sn, tpx, tpy, plane);
            else
                compute_store<false>(&pl[0][0][0], outb, tid, ox0, oy0, bx0c, by0, cs, sn, tpx, tpy, plane);
        } else {
            fallback_tile(imb, outb, tid, ox0, oy0, cs, sn, tpx, tpy, plane);
        }
        __syncthreads();                   // all waves done reading LDS

        if (tt + 1 < NT) {
            lds_write(sn_, dnext, &pl[0][0][0], q, ql);   // vmcnt drain here
            dcur = dnext;
        }
        __syncthreads();                   // LDS ready for next tile
    }
}

extern "C" void kernel_launch(void* const* d_in, const int* in_sizes, int n_in,
                              void* d_out, int out_size, void* d_ws, size_t ws_size,
                              hipStream_t stream) {
    const float* img   = (const float*)d_in[0];
    const float* rot   = (const float*)d_in[1];
    const float* trans = (const float*)d_in[2];
    const float* scale = (const float*)d_in[3];
    float* out = (float*)d_out;
    float* ws  = (float*)d_ws;

    warp_setup<<<dim3(BB), 256, 0, stream>>>(rot, trans, scale, ws);
    warp_tiled<<<dim3(BB * 64), 512, 0, stream>>>(img, ws, out);
}

// Round 14
// 67.263 us; speedup vs baseline: 1.2618x; 1.2618x over previous
//
#include <hip/hip_runtime.h>
#include <stdint.h>

#define BB 64
#define CC 3
#define HH 512
#define WW 512
#define TILE 32
#define MAXBH 48
#define MAXBW 52
#define PLST 56  // plane row stride (dwords): 56 % 32 == 24 -> row-pair gives exact 2-cover of banks

typedef float f32x4 __attribute__((ext_vector_type(4)));

__device__ __forceinline__ void pix2in(float x, float y,
                                       float cs, float sn, float tx, float ty,
                                       float& ix, float& iy)
{
    float gx = (2.0f * x + 1.0f) * (1.0f / (float)WW) - 1.0f;
    float gy = (2.0f * y + 1.0f) * (1.0f / (float)HH) - 1.0f;
    float gxt = cs * gx - sn * gy + tx;
    float gyt = sn * gx + cs * gy + ty;
    ix = ((gxt + 1.0f) * (float)WW - 1.0f) * 0.5f;
    iy = ((gyt + 1.0f) * (float)HH - 1.0f) * 0.5f;
}

// ws layout: float prm[64*4] (cs,sn,tx,ty per batch), then uint32 desc[16384]
__global__ __launch_bounds__(256) void warp_setup(
    const float* __restrict__ rot, const float* __restrict__ trans,
    const float* __restrict__ scale, float* __restrict__ ws)
{
    const int i = blockIdx.x * 256 + threadIdx.x;   // 0..16383 = b*256+t
    const int b = i >> 8, t = i & 255;
    const float r = rot[b];
    const float inv_s = 1.0f / scale[b];
    const float cs = cosf(r) * inv_s;
    const float sn = sinf(r) * inv_s;
    const float tx = trans[2 * b], ty = trans[2 * b + 1];
    if (t == 0)
        reinterpret_cast<float4*>(ws)[b] = make_float4(cs, sn, tx, ty);

    const int oy0 = (t >> 4) * TILE;
    const int ox0 = (t & 15) * TILE;
    float ixa, iya, ixb, iyb, ixc, iyc, ixd, iyd;
    pix2in((float)ox0,              (float)oy0,              cs, sn, tx, ty, ixa, iya);
    pix2in((float)(ox0 + TILE - 1), (float)oy0,              cs, sn, tx, ty, ixb, iyb);
    pix2in((float)ox0,              (float)(oy0 + TILE - 1), cs, sn, tx, ty, ixc, iyc);
    pix2in((float)(ox0 + TILE - 1), (float)(oy0 + TILE - 1), cs, sn, tx, ty, ixd, iyd);
    const float minix = fminf(fminf(ixa, ixb), fminf(ixc, ixd));
    const float maxix = fmaxf(fmaxf(ixa, ixb), fmaxf(ixc, ixd));
    const float miniy = fminf(fminf(iya, iyb), fminf(iyc, iyd));
    const float maxiy = fmaxf(fmaxf(iya, iyb), fmaxf(iyc, iyd));
    const int bx0 = (int)floorf(minix) - 1;
    const int bx1 = (int)floorf(maxix) + 2;
    const int by0 = (int)floorf(miniy) - 1;
    const int by1 = (int)floorf(maxiy) + 2;
    int bx0c = bx0 & ~3;
    const int bw = bx1 - bx0c + 1;
    const int bh = by1 - by0 + 1;

    const uint32_t fit      = (bw <= MAXBW && bh <= MAXBH) ? 1u : 0u;
    const uint32_t interior = (bx0c >= 0 && bx1 < WW && by0 >= 0 && by1 < HH) ? 1u : 0u;
    const int bx0s = min(max(bx0c, -2048), 2047);
    const int by0s = min(max(by0,  -2048), 2047);
    const int bhs  = min(bh, 63);
    const uint32_t desc = ((uint32_t)bx0s & 0xFFFu)
                        | (((uint32_t)by0s & 0xFFFu) << 12)
                        | ((uint32_t)bhs << 24)
                        | (fit << 30) | (interior << 31);
    reinterpret_cast<uint32_t*>(ws)[256 + i] = desc;
}

template <bool INTERIOR>
__device__ __forceinline__ void compute_store(
    const float* __restrict__ pl, float* __restrict__ outb,
    int tid, int ox0, int oy0, int bx0c, int by0,
    float cs, float sn, float tpx, float tpy, long plane)
{
    const int ry = tid >> 5;             // 0..15
    const int xp = tid & 31;             // 0..31  (lane stride 1 in x!)
    const int ox = ox0 + xp;

    float ix0, iy0;
    pix2in((float)ox, (float)(oy0 + ry), cs, sn, tpx, tpy, ix0, iy0);

    #pragma unroll
    for (int h = 0; h < 2; ++h) {
        // second half: +16 output rows; affine: d(ix)/dy = -sn, d(iy)/dy = +cs
        const float ix = fmaf((float)(16 * h), -sn, ix0);
        const float iy = fmaf((float)(16 * h),  cs, iy0);
        const float x0f = floorf(ix), y0f = floorf(iy);
        const float wx1 = ix - x0f,  wy1 = iy - y0f;
        const float wx0 = 1.0f - wx1, wy0 = 1.0f - wy1;
        const int x0 = (int)x0f, y0 = (int)y0f;

        float w00 = wy0 * wx0, w01 = wy0 * wx1, w10 = wy1 * wx0, w11 = wy1 * wx1;
        if (!INTERIOR) {
            const int x1 = x0 + 1, y1 = y0 + 1;
            const float vx0 = (x0 >= 0 && x0 < WW) ? 1.0f : 0.0f;
            const float vx1 = (x1 >= 0 && x1 < WW) ? 1.0f : 0.0f;
            const float vy0 = (y0 >= 0 && y0 < HH) ? 1.0f : 0.0f;
            const float vy1 = (y1 >= 0 && y1 < HH) ? 1.0f : 0.0f;
            w00 *= vy0 * vx0; w01 *= vy0 * vx1; w10 *= vy1 * vx0; w11 *= vy1 * vx1;
        }

        const int idx = (y0 - by0) * PLST + (x0 - bx0c);   // margin guarantees in-range
        const float* pb = pl + idx;
        const int oy = oy0 + ry + 16 * h;
        const long ob = (long)oy * WW + ox;
        #pragma unroll
        for (int c = 0; c < CC; ++c) {
            const float* pc = pb + c * (MAXBH * PLST);     // channel via byte immediate
            const float v = w00 * pc[0] + w01 * pc[1]
                          + w10 * pc[PLST] + w11 * pc[PLST + 1];
            __builtin_nontemporal_store(v, outb + c * plane + ob);
        }
    }
}

__global__ __launch_bounds__(512) void warp_tiled(
    const float* __restrict__ img, const float* __restrict__ ws,
    float* __restrict__ out)
{
    __shared__ __align__(16) float pl[CC][MAXBH][PLST];   // 32.3 KB, 3 channel planes

    // XCD chunk swizzle: each XCD owns 8 whole batches
    const int g   = blockIdx.x;
    const int swz = (g & 7) * ((BB * 256) / 8) + (g >> 3);
    const int b   = swz >> 8;
    const int t   = swz & 255;
    const int oy0 = (t >> 4) * TILE;
    const int ox0 = (t & 15) * TILE;

    const float4 p = reinterpret_cast<const float4*>(ws)[b];
    const float cs = p.x, sn = p.y, tpx = p.z, tpy = p.w;
    const uint32_t desc = reinterpret_cast<const uint32_t*>(ws)[256 + swz];
    const int  bx0c     = ((int)(desc << 20)) >> 20;
    const int  by0      = ((int)(desc << 8))  >> 20;
    const int  bh       = (desc >> 24) & 63;
    const bool fit      = (desc >> 30) & 1;
    const bool interior = (desc >> 31) & 1;

    const long plane = (long)HH * WW;
    const float* imb = img + (long)b * CC * plane;
    float* outb      = out + (long)b * CC * plane;
    const int tid = threadIdx.x;

    if (fit) {
        const int q  = tid >> 4;          // 0..31 row group
        const int ql = tid & 15;          // 13 active lanes cover 52 cols
        if (ql < 13) {
            const int xb = ql * 4;        // col offset within bbox, 16B-aligned slot
            if (interior && (bx0c + 51 < WW)) {
                for (int r = q; r < bh; r += 32) {
                    const float* pr = imb + (long)(by0 + r) * WW + (bx0c + xb);
                    const f32x4 a = *reinterpret_cast<const f32x4*>(pr);
                    const f32x4 bv = *reinterpret_cast<const f32x4*>(pr + plane);
                    const f32x4 cv = *reinterpret_cast<const f32x4*>(pr + 2 * plane);
                    *reinterpret_cast<f32x4*>(&pl[0][r][xb]) = a;    // contiguous b128
                    *reinterpret_cast<f32x4*>(&pl[1][r][xb]) = bv;
                    *reinterpret_cast<f32x4*>(&pl[2][r][xb]) = cv;
                }
            } else {
                for (int r = q; r < bh; r += 32) {
                    const int grow = by0 + r;
                    const bool rowok = (grow >= 0) && (grow < HH);
                    const float* pr = imb + (long)grow * WW;
                    f32x4 a = {0.f, 0.f, 0.f, 0.f}, bv = a, cv = a;
                    #pragma unroll
                    for (int k = 0; k < 4; ++k) {
                        const int gcol = bx0c + xb + k;
                        if (rowok && gcol >= 0 && gcol < WW) {
                            a[k]  = pr[gcol];
                            bv[k] = pr[(long)gcol + plane];
                            cv[k] = pr[(long)gcol + 2 * plane];
                        }
                    }
                    *reinterpret_cast<f32x4*>(&pl[0][r][xb]) = a;
                    *reinterpret_cast<f32x4*>(&pl[1][r][xb]) = bv;
                    *reinterpret_cast<f32x4*>(&pl[2][r][xb]) = cv;
                }
            }
        }
        __syncthreads();

        if (interior)
            compute_store<true >(&pl[0][0][0], outb, tid, ox0, oy0, bx0c, by0, cs, sn, tpx, tpy, plane);
        else
            compute_store<false>(&pl[0][0][0], outb, tid, ox0, oy0, bx0c, by0, cs, sn, tpx, tpy, plane);
    } else {
        // ---- fallback: direct global gather (never taken for scale=1) ----
        #pragma unroll
        for (int k = 0; k < 2; ++k) {
            const int pidx = tid + k * 512;
            const int py = pidx >> 5;
            const int px = pidx & 31;
            const int ox = ox0 + px, oy = oy0 + py;

            float ix, iy;
            pix2in((float)ox, (float)oy, cs, sn, tpx, tpy, ix, iy);
            const float x0f = floorf(ix), y0f = floorf(iy);
            const float wx1 = ix - x0f,  wy1 = iy - y0f;
            const int x0 = (int)x0f, y0 = (int)y0f;
            const int x1 = x0 + 1,  y1 = y0 + 1;

            const float vx0 = (x0 >= 0 && x0 < WW) ? 1.0f : 0.0f;
            const float vx1 = (x1 >= 0 && x1 < WW) ? 1.0f : 0.0f;
            const float vy0 = (y0 >= 0 && y0 < HH) ? 1.0f : 0.0f;
            const float vy1 = (y1 >= 0 && y1 < HH) ? 1.0f : 0.0f;

            const int x0c = min(max(x0, 0), WW - 1);
            const int x1c = min(max(x1, 0), WW - 1);
            const int y0c = min(max(y0, 0), HH - 1);
            const int y1c = min(max(y1, 0), HH - 1);

            const float w00 = (1.0f - wy1) * (1.0f - wx1) * vy0 * vx0;
            const float w01 = (1.0f - wy1) * wx1          * vy0 * vx1;
            const float w10 = wy1          * (1.0f - wx1) * vy1 * vx0;
            const float w11 = wy1          * wx1          * vy1 * vx1;

            const int o00 = y0c * WW + x0c, o01 = y0c * WW + x1c;
            const int o10 = y1c * WW + x0c, o11 = y1c * WW + x1c;
            const int ob = oy * WW + ox;
            #pragma unroll
            for (int c = 0; c < CC; ++c) {
                const float* pc = imb + (long)c * plane;
                const float v = w00 * pc[o00] + w01 * pc[o01]
                              + w10 * pc[o10] + w11 * pc[o11];
                __builtin_nontemporal_store(v, &outb[(long)c * plane + ob]);
            }
        }
    }
}

extern "C" void kernel_launch(void* const* d_in, const int* in_sizes, int n_in,
                              void* d_out, int out_size, void* d_ws, size_t ws_size,
                              hipStream_t stream) {
    const float* img   = (const float*)d_in[0];
    const float* rot   = (const float*)d_in[1];
    const float* trans = (const float*)d_in[2];
    const float* scale = (const float*)d_in[3];
    float* out = (float*)d_out;
    float* ws  = (float*)d_ws;

    warp_setup<<<dim3(BB), 256, 0, stream>>>(rot, trans, scale, ws);
    warp_tiled<<<dim3(BB * 256), 512, 0, stream>>>(img, ws, out);
}